// Round 2
// baseline (280.530 us; speedup 1.0000x reference)
//
#include <hip/hip_runtime.h>

#define T_DIM 8192
#define D_DIM 1024
#define H_DIM 2048
#define N_DIM 4096
#define CHUNK 32
#define LOG2_CHUNK 5
#define NCH   (T_DIM / CHUNK)   // 256

typedef __attribute__((ext_vector_type(8))) short bf16x8;
typedef __attribute__((ext_vector_type(4))) float f32x4;

// ---------------- helpers ----------------

__device__ __forceinline__ unsigned short f2bf(float f) {
    unsigned int u = __float_as_uint(f);
    unsigned int r = (u + 0x7fffu + ((u >> 16) & 1u)) >> 16;  // RNE
    return (unsigned short)r;
}

__device__ __forceinline__ float blo(unsigned int u) { return __uint_as_float(u << 16); }
__device__ __forceinline__ float bhi(unsigned int u) { return __uint_as_float(u & 0xffff0000u); }
__device__ __forceinline__ float bf2f(unsigned short u) {
    return __uint_as_float((unsigned int)u << 16);
}

__device__ __forceinline__ void gl_lds16(const unsigned short* g, unsigned short* l) {
    __builtin_amdgcn_global_load_lds(
        (__attribute__((address_space(1))) void*)(g),
        (__attribute__((address_space(3))) void*)(l), 16, 0, 0);
}

// complex rotate-accumulate: (H1+iH2) = (A+iB)(H1+iH2) + (V1+iV2)
#define CSTEP(A, Bq, H1, H2, V1, V2)                  \
    {                                                 \
        float n1 = (A) * (H1) - (Bq) * (H2) + (V1);   \
        float n2 = (A) * (H2) + (Bq) * (H1) + (V2);   \
        (H1) = n1; (H2) = n2;                         \
    }

// ---------------- kernel 1: per-channel params ----------------

__global__ void params_kernel(const float* __restrict__ lamda,
                              const float* __restrict__ theta,
                              float* __restrict__ pa, float* __restrict__ pb,
                              float* __restrict__ pg) {
    int h = blockIdx.x * 256 + threadIdx.x;
    if (h >= H_DIM) return;
    float y = expf(-expf(lamda[h]));
    float z = expf(theta[h]);
    pg[h] = sqrtf(1.0f - y * y);
    pa[h] = y * cosf(z);
    pb[h] = y * sinf(z);
}

// ---------------- kernel 2a: x fp32->bf16 ----------------

__global__ void cvt_x(const float4* __restrict__ s, ushort4* __restrict__ d, int n4) {
    int i = blockIdx.x * 256 + threadIdx.x;
    if (i >= n4) return;
    float4 f = s[i];
    ushort4 o;
    o.x = f2bf(f.x); o.y = f2bf(f.y); o.z = f2bf(f.z); o.w = f2bf(f.w);
    d[i] = o;
}

// ---------------- kernel 2b: B1/B2 fp32->bf16 ----------------
// inter=1: per-channel interleave — dest row = 2*h + comp (so GEMM tile col
//          == V col == 2*ch+comp). inter=0: contiguous [B1; B2] (fallback).

__global__ void cvt_B(const float4* __restrict__ s1, const float4* __restrict__ s2,
                      ushort4* __restrict__ d, int inter) {
    const int n = H_DIM * D_DIM / 4;   // groups per matrix
    int i = blockIdx.x * 256 + threadIdx.x;
    const float4* s; int comp, j;
    if (i < n) { s = s1; comp = 0; j = i; }
    else if (i < 2 * n) { s = s2; comp = 1; j = i - n; }
    else return;
    float4 f = s[j];
    ushort4 o;
    o.x = f2bf(f.x); o.y = f2bf(f.y); o.z = f2bf(f.z); o.w = f2bf(f.w);
    int h = j >> 8;          // 256 float4-groups per 1024-row
    int d4 = j & 255;
    int drow = inter ? (h * 2 + comp)
                     : (comp * H_DIM + h);
    d[(size_t)drow * 256 + d4] = o;
}

// ---------------- kernel 3 (fused path): 256x256 8-phase GEMM + scan epilogue ----
// BM=BN=256, BK=64 (2 K-tiles/iter), 8 waves (2M x 4N), 512 threads, 128 KiB LDS.
// LDS map (ushorts): A-even @0, B-even @16384, A-odd @32768, B-odd @49152.
// Stage placement = max-distance: each region staged right after its last-reader
// phase (A-even read P0/P2 -> staged P4/P5; B-even read P0/P1 -> staged P2/P3;
// A-odd read P4/P6 -> staged prev-iter P7; B-odd read P4/P5 -> staged P6/P7).
// vmcnt(4) at P3 (waits loads issued >=4 phases back), vmcnt(8) at P7.

#define PH_BAR  __builtin_amdgcn_s_barrier()
#define LGKM0   asm volatile("s_waitcnt lgkmcnt(0)" ::: "memory")
#define VMC4    asm volatile("s_waitcnt vmcnt(4)" ::: "memory")
#define VMC8    asm volatile("s_waitcnt vmcnt(8)" ::: "memory")
#define VMC0    asm volatile("s_waitcnt vmcnt(0)" ::: "memory")

#define LDA(ABASE, MIB)                                                           \
    { _Pragma("unroll") for (int u = 0; u < 4; ++u)                               \
        { _Pragma("unroll") for (int ks = 0; ks < 2; ++ks)                        \
            af[u][ks] = *(const bf16x8*)&smem[(ABASE) + ks * 8192 + aRd + ((MIB) + u) * 512]; } }

#define LDB(BBASE, NIB)                                                           \
    { _Pragma("unroll") for (int u = 0; u < 2; ++u)                               \
        { _Pragma("unroll") for (int ks = 0; ks < 2; ++ks)                        \
            bfr[(NIB) + u][ks] = *(const bf16x8*)&smem[(BBASE) + ks * 8192 + bRd + ((NIB) + u) * 512]; } }

#define MFQ(MIB, NIB)                                                             \
    { __builtin_amdgcn_s_setprio(1);                                              \
      _Pragma("unroll") for (int mi2 = 0; mi2 < 4; ++mi2)                         \
        { _Pragma("unroll") for (int ni2 = 0; ni2 < 2; ++ni2)                     \
            { _Pragma("unroll") for (int ks = 0; ks < 2; ++ks)                    \
                acc[(MIB) + mi2][(NIB) + ni2] = __builtin_amdgcn_mfma_f32_16x16x32_bf16( \
                    af[mi2][ks], bfr[(NIB) + ni2][ks], acc[(MIB) + mi2][(NIB) + ni2], 0, 0, 0); } } \
      __builtin_amdgcn_s_setprio(0); }

#define STG(SRC, LBASE, HALF, KOFF)                                               \
    { gl_lds16((SRC) + (size_t)(HALF) * 128 * D_DIM + (KOFF),                     \
               &smem[(LBASE) + (HALF) * 4096 + ldsT]);                            \
      gl_lds16((SRC) + (size_t)(HALF) * 128 * D_DIM + (KOFF) + 32,                \
               &smem[(LBASE) + 8192 + (HALF) * 4096 + ldsT]); }

__global__ __launch_bounds__(512, 2) void gemm_fused256(
    const unsigned short* __restrict__ A,    // [8192,1024] bf16
    const unsigned short* __restrict__ Bi,   // interleaved [4096,1024] bf16
    const float* __restrict__ gamma,         // [2048]
    const float* __restrict__ pa, const float* __restrict__ pb,
    unsigned short* __restrict__ V,          // bf16 [8192][4096] (col = 2*ch+comp)
    float* __restrict__ E)                   // [256][4096]
{
    __shared__ unsigned short smem[65536];   // 128 KiB (staging; epilogue aliases as tile)

    const int tid  = threadIdx.x;
    const int lane = tid & 63;
    const int wave = tid >> 6;
    const int quad = lane >> 4;
    const int m16  = lane & 15;
    const int wr   = wave >> 2;   // 0..1 (M)
    const int wc   = wave & 3;    // 0..3 (N)

    // XCD-aware swizzle: XCD k owns a 4-wide bx strip (A slice 2 MiB -> L2-resident).
    // fid%8 == XCD (round-robin dispatch); bijective over 512 blocks.
    const int fid = blockIdx.y * 32 + blockIdx.x;
    const int xcd = fid & 7;
    const int c_  = fid >> 3;            // 0..63
    const int bx  = xcd * 4 + (c_ & 3);  // 0..31
    const int by  = c_ >> 2;             // 0..15

    const int rowA0 = bx * 256;
    const int rowB0 = by * 256;
    const int ch0   = by * 128;

    // staging source mapping (per-thread, linear-lane LDS dest)
    const int r_loc = tid >> 2;                          // 0..127
    const int kg    = ((tid & 3) ^ ((r_loc >> 1) & 3)) * 8;
    const unsigned short* aSrc = A  + (size_t)(rowA0 + r_loc) * D_DIM + kg;
    const unsigned short* bSrc = Bi + (size_t)(rowB0 + r_loc) * D_DIM + kg;
    const int ldsT = tid * 8;

    // fragment read offsets (proven conflict-free pattern)
    const int grp8 = (quad ^ ((m16 >> 1) & 3)) * 8;
    const int aRd  = (wr * 128 + m16) * 32 + grp8;
    const int bRd  = (wc * 64 + m16) * 32 + grp8;

    f32x4 acc[8][4];
#pragma unroll
    for (int i = 0; i < 8; i++)
#pragma unroll
        for (int j = 0; j < 4; j++) acc[i][j] = (f32x4)(0.0f);

    bf16x8 af[4][2], bfr[4][2];

    // prologue: even tile first (oldest), then odd tile
    STG(bSrc, 16384, 0, 0);  STG(bSrc, 16384, 1, 0);
    STG(aSrc, 0, 0, 0);      STG(aSrc, 0, 1, 0);
    STG(bSrc, 49152, 0, 64); STG(bSrc, 49152, 1, 64);
    STG(aSrc, 32768, 0, 64); STG(aSrc, 32768, 1, 64);
    VMC8;                    // even tile's 8 loads done (odd tile still in flight)
    PH_BAR;

#pragma unroll 1
    for (int j = 0; j < 8; ++j) {
        const int k0 = j * 128;
        // ---- P0 ----
        LDA(0, 0); LDB(16384, 0);
        PH_BAR; LGKM0;
        MFQ(0, 0);
        PH_BAR;
        // ---- P1 ----
        LDB(16384, 2);
        PH_BAR; LGKM0;
        MFQ(0, 2);
        PH_BAR;
        // ---- P2 ---- (B-even last read was P1 -> stage next B-even)
        LDA(0, 4);
        if (j < 7) STG(bSrc, 16384, 0, k0 + 128);
        PH_BAR; LGKM0;
        MFQ(4, 0);
        PH_BAR;
        // ---- P3 ----
        if (j < 7) STG(bSrc, 16384, 1, k0 + 128);
        PH_BAR;
        MFQ(4, 2);
        if (j < 7) { VMC4; } else { VMC0; }   // odd tile (issued >=4 phases ago) ready
        PH_BAR;
        // ---- P4 ---- (A-even last read was P2 -> stage next A-even)
        LDA(32768, 0); LDB(49152, 0);
        if (j < 7) STG(aSrc, 0, 0, k0 + 128);
        PH_BAR; LGKM0;
        MFQ(0, 0);
        PH_BAR;
        // ---- P5 ----
        LDB(49152, 2);
        if (j < 7) STG(aSrc, 0, 1, k0 + 128);
        PH_BAR; LGKM0;
        MFQ(0, 2);
        PH_BAR;
        // ---- P6 ---- (B-odd last read was P5 -> stage next B-odd)
        LDA(32768, 4);
        if (j < 7) STG(bSrc, 49152, 0, k0 + 192);
        PH_BAR; LGKM0;
        MFQ(4, 0);
        PH_BAR;
        // ---- P7 ---- (A-odd last read was P6 -> stage next A-odd here too)
        if (j < 7) {
            STG(bSrc, 49152, 1, k0 + 192);
            STG(aSrc, 32768, 0, k0 + 192);
            STG(aSrc, 32768, 1, k0 + 192);
        }
        PH_BAR;
        MFQ(4, 2);
        if (j < 7) { VMC8; }                  // even-next (issued P2..P5) ready
        PH_BAR;
    }

    __syncthreads();   // full drain; smem reused as 256x256 bf16 output tile

    // ---- acc -> LDS tile (bf16, gamma-scaled), stride 256, quad-XOR col swizzle ----
    // t = wr*128 + mi*16 + quad*4 + r ; col = wc*64 + ni*16 + m16
    // tile col c -> channel ch0 + (c>>1), comp = c&1
#pragma unroll
    for (int ni = 0; ni < 4; ni++) {
        const int col = wc * 64 + ni * 16 + m16;
        const float g = gamma[ch0 + (col >> 1)];
#pragma unroll
        for (int mi = 0; mi < 8; mi++) {
#pragma unroll
            for (int r = 0; r < 4; r++) {
                const int t  = wr * 128 + mi * 16 + quad * 4 + r;
                const int sw = (((t >> 2) & 3) * 48) & 63;
                smem[t * 256 + (col ^ sw)] = f2bf(acc[mi][ni][r] * g);
            }
        }
    }
    __syncthreads();

    // ---- chunk-local scans: 512 threads = 128 channels x 4 chunk-slots, 2 chunks each.
    // Channel chl lives at adjacent tile cols (2chl, 2chl+1) -> one u32 read/step.
    {
        const int chl = tid & 127;
        const int ck4 = tid >> 7;                               // 0..3
        const float wa = pa[ch0 + chl], wb = pb[ch0 + chl];
        const int cbase = chl * 2;
#pragma unroll
        for (int cc = 0; cc < 2; cc++) {
            const int c = ck4 + cc * 4;                         // chunk in block 0..7
            float e1 = 0.f, e2 = 0.f;
#pragma unroll
            for (int jj = 0; jj < CHUNK; jj++) {
                const int t  = c * CHUNK + jj;
                const int sw = (((t >> 2) & 3) * 48) & 63;      // wave-uniform
                unsigned int u = *(const unsigned int*)&smem[t * 256 + (cbase ^ sw)];
                float v1 = blo(u), v2 = bhi(u);
                CSTEP(wa, wb, e1, e2, v1, v2);
            }
            const int cg = bx * 8 + c;
            E[(size_t)cg * N_DIM + ch0 + chl]         = e1;
            E[(size_t)cg * N_DIM + H_DIM + ch0 + chl] = e2;
        }
    }

    // ---- stream tile -> V (bf16, 16B stores). Identity col mapping: V col = by*256 + c.
#pragma unroll
    for (int s = 0; s < 16; s++) {
        const int g     = s * 512 + tid;
        const int row   = g >> 5;
        const int col16 = (g & 31) * 8;
        const int sw    = (((row >> 2) & 3) * 48) & 63;
        uint4 val = *(const uint4*)&smem[row * 256 + (col16 ^ sw)];
        *(uint4*)&V[(size_t)(rowA0 + row) * N_DIM + by * 256 + col16] = val;
    }
}

// ---------------- kernel 3 (fallback): R5 gemm ----------------

template <bool BF16OUT>
__global__ __launch_bounds__(256) void gemm_bt(
    const unsigned short* __restrict__ A, const unsigned short* __restrict__ B,
    const float* __restrict__ gamma, void* __restrict__ Cv)
{
    __shared__ unsigned short sA[128 * 32];
    __shared__ unsigned short sB[128 * 32];

    const int tid  = threadIdx.x;
    const int lane = tid & 63;
    const int wave = tid >> 6;
    const int quad = lane >> 4;
    const int m16  = lane & 15;
    const int wm = (wave >> 1) << 6;
    const int wn = (wave & 1) << 6;
    const int rowA0 = blockIdx.x * 128;
    const int rowB0 = blockIdx.y * 128;
    const int e0 = tid * 8;
    const int r0 = e0 >> 5;
    const int gs = (e0 >> 3) & 3;
    const int k0 = (gs ^ ((r0 >> 1) & 3)) * 8;
    const int r1 = r0 + 64;
    const unsigned short* a0 = A + (size_t)(rowA0 + r0) * D_DIM + k0;
    const unsigned short* a1 = A + (size_t)(rowA0 + r1) * D_DIM + k0;
    const unsigned short* b0 = B + (size_t)(rowB0 + r0) * D_DIM + k0;
    const unsigned short* b1 = B + (size_t)(rowB0 + r1) * D_DIM + k0;
    unsigned short* la0 = &sA[e0];
    unsigned short* la1 = &sA[e0 + 2048];
    unsigned short* lb0 = &sB[e0];
    unsigned short* lb1 = &sB[e0 + 2048];
    const int grp8 = (quad ^ ((m16 >> 1) & 3)) * 8;

    f32x4 acc[4][4];
#pragma unroll
    for (int i = 0; i < 4; i++)
#pragma unroll
        for (int j = 0; j < 4; j++) acc[i][j] = (f32x4)(0.0f);

    for (int kt = 0; kt < D_DIM; kt += 32) {
        __syncthreads();
        gl_lds16(a0 + kt, la0);
        gl_lds16(a1 + kt, la1);
        gl_lds16(b0 + kt, lb0);
        gl_lds16(b1 + kt, lb1);
        __syncthreads();
        bf16x8 af2[4], bfr2[4];
#pragma unroll
        for (int i = 0; i < 4; i++)
            af2[i] = *(const bf16x8*)&sA[(wm + i * 16 + m16) * 32 + grp8];
#pragma unroll
        for (int i = 0; i < 4; i++)
            bfr2[i] = *(const bf16x8*)&sB[(wn + i * 16 + m16) * 32 + grp8];
#pragma unroll
        for (int mi = 0; mi < 4; mi++)
#pragma unroll
            for (int ni = 0; ni < 4; ni++)
                acc[mi][ni] = __builtin_amdgcn_mfma_f32_16x16x32_bf16(
                    af2[mi], bfr2[ni], acc[mi][ni], 0, 0, 0);
    }

    float* Cf = (float*)Cv;
    unsigned short* Cb = (unsigned short*)Cv;
#pragma unroll
    for (int ni = 0; ni < 4; ni++) {
        const int col = rowB0 + wn + ni * 16 + m16;
        const float g = gamma[col & (H_DIM - 1)];
#pragma unroll
        for (int mi = 0; mi < 4; mi++) {
            const int row0 = rowA0 + wm + mi * 16 + quad * 4;
#pragma unroll
            for (int r = 0; r < 4; r++) {
                float val = acc[mi][ni][r] * g;
                if (BF16OUT) Cb[(size_t)(row0 + r) * N_DIM + col] = f2bf(val);
                else         Cf[(size_t)(row0 + r) * N_DIM + col] = val;
            }
        }
    }
}

// ---------------- kernel 4a (fallback): chunk-local end states ----------------

template <bool BF16IN>
__global__ void scanA(const void* __restrict__ v,
                      const float* __restrict__ pa, const float* __restrict__ pb,
                      float* __restrict__ E) {
    int h4 = (blockIdx.x * 256 + threadIdx.x) * 4;
    int c = blockIdx.y;
    float4 a = *(const float4*)(pa + h4);
    float4 b = *(const float4*)(pb + h4);
    float4 h1 = make_float4(0.f, 0.f, 0.f, 0.f);
    float4 h2 = make_float4(0.f, 0.f, 0.f, 0.f);
    const unsigned short* pb16 = (const unsigned short*)v + (size_t)c * CHUNK * N_DIM + h4;
    const float* pf = (const float*)v + (size_t)c * CHUNK * N_DIM + h4;
#pragma unroll 8
    for (int t = 0; t < CHUNK; t++) {
        float4 v1, v2;
        if (BF16IN) {
            uint2 u1 = *(const uint2*)(pb16);
            uint2 u2 = *(const uint2*)(pb16 + H_DIM);
            v1 = make_float4(blo(u1.x), bhi(u1.x), blo(u1.y), bhi(u1.y));
            v2 = make_float4(blo(u2.x), bhi(u2.x), blo(u2.y), bhi(u2.y));
            pb16 += N_DIM;
        } else {
            v1 = *(const float4*)(pf);
            v2 = *(const float4*)(pf + H_DIM);
            pf += N_DIM;
        }
        CSTEP(a.x, b.x, h1.x, h2.x, v1.x, v2.x);
        CSTEP(a.y, b.y, h1.y, h2.y, v1.y, v2.y);
        CSTEP(a.z, b.z, h1.z, h2.z, v1.z, v2.z);
        CSTEP(a.w, b.w, h1.w, h2.w, v1.w, v2.w);
    }
    *(float4*)(E + (size_t)c * N_DIM + h4)         = h1;
    *(float4*)(E + (size_t)c * N_DIM + H_DIM + h4) = h2;
}

// ---------------- kernel 4b: wave-parallel carry scan (one wave per channel) ----------------

__global__ __launch_bounds__(256) void scanB_wave(
    const float* __restrict__ pa, const float* __restrict__ pb,
    const float* __restrict__ E, float* __restrict__ P) {
    const int lane = threadIdx.x & 63;
    const int ch   = blockIdx.x * 4 + (threadIdx.x >> 6);
    const float ca = pa[ch], cb = pb[ch];
    float Wr = ca, Wi = cb;
#pragma unroll
    for (int j = 0; j < LOG2_CHUNK; j++) {
        float nr = Wr * Wr - Wi * Wi, ni = 2.f * Wr * Wi;
        Wr = nr; Wi = ni;
    }
    float Sr[4], Si[4];
    float sr = 0.f, si = 0.f;
#pragma unroll
    for (int k = 0; k < 4; k++) {
        int cc = 4 * lane + k;
        float e1 = E[(size_t)cc * N_DIM + ch];
        float e2 = E[(size_t)cc * N_DIM + H_DIM + ch];
        float nr = Wr * sr - Wi * si + e1;
        float ni = Wr * si + Wi * sr + e2;
        sr = nr; si = ni;
        Sr[k] = sr; Si[k] = si;
    }
    float vr = sr, vi = si;
    float W4r = Wr * Wr - Wi * Wi, W4i = 2.f * Wr * Wi;
    { float nr = W4r * W4r - W4i * W4i, ni = 2.f * W4r * W4i;
      W4r = nr; W4i = ni; }
    float stepR = W4r, stepI = W4i;
#pragma unroll
    for (int d = 1; d < 64; d <<= 1) {
        float tr = __shfl_up(vr, d, 64);
        float ti = __shfl_up(vi, d, 64);
        float nr = stepR * tr - stepI * ti + vr;
        float ni = stepR * ti + stepI * tr + vi;
        if (lane >= d) { vr = nr; vi = ni; }
        float r2 = stepR * stepR - stepI * stepI;
        float i2 = 2.f * stepR * stepI;
        stepR = r2; stepI = i2;
    }
    float txr = __shfl_up(vr, 1, 64);
    float txi = __shfl_up(vi, 1, 64);
    if (lane == 0) { txr = 0.f; txi = 0.f; }
    P[(size_t)(4 * lane) * N_DIM + ch]         = txr;
    P[(size_t)(4 * lane) * N_DIM + H_DIM + ch] = txi;
    float qr = txr, qi = txi;
#pragma unroll
    for (int k = 1; k < 4; k++) {
        float nr = Wr * qr - Wi * qi;
        float ni = Wr * qi + Wi * qr;
        qr = nr; qi = ni;
        P[(size_t)(4 * lane + k) * N_DIM + ch]         = qr + Sr[k - 1];
        P[(size_t)(4 * lane + k) * N_DIM + H_DIM + ch] = qi + Si[k - 1];
    }
}

// ---------------- kernel 4c (fused path): final scan, interleaved V, uint4 loads ----

__global__ void scanC_int(const unsigned short* __restrict__ v, float* __restrict__ out,
                          const float* __restrict__ pa, const float* __restrict__ pb,
                          const float* __restrict__ P) {
    int ch4 = (blockIdx.x * 256 + threadIdx.x) * 4;
    int c = blockIdx.y;
    f32x4 a = *(const f32x4*)(pa + ch4);
    f32x4 b = *(const f32x4*)(pb + ch4);
    f32x4 h1 = *(const f32x4*)(P + (size_t)c * N_DIM + ch4);
    f32x4 h2 = *(const f32x4*)(P + (size_t)c * N_DIM + H_DIM + ch4);
    const unsigned short* pv = v + (size_t)c * CHUNK * N_DIM + (size_t)ch4 * 2;
    float* po = out + (size_t)c * CHUNK * N_DIM + ch4;
#pragma unroll 8
    for (int t = 0; t < CHUNK; t++) {
        uint4 u = *(const uint4*)pv;
        f32x4 v1 = {blo(u.x), blo(u.y), blo(u.z), blo(u.w)};
        f32x4 v2 = {bhi(u.x), bhi(u.y), bhi(u.z), bhi(u.w)};
        CSTEP(a.x, b.x, h1.x, h2.x, v1.x, v2.x);
        CSTEP(a.y, b.y, h1.y, h2.y, v1.y, v2.y);
        CSTEP(a.z, b.z, h1.z, h2.z, v1.z, v2.z);
        CSTEP(a.w, b.w, h1.w, h2.w, v1.w, v2.w);
        __builtin_nontemporal_store(h1, (f32x4*)(po));
        __builtin_nontemporal_store(h2, (f32x4*)(po + H_DIM));
        pv += N_DIM; po += N_DIM;
    }
}

// ---------------- kernel 4c (fallback): final scan, separate-comp layout ----------------

template <bool BF16IN>
__global__ void scanC(const void* __restrict__ v, float* __restrict__ out,
                      const float* __restrict__ pa, const float* __restrict__ pb,
                      const float* __restrict__ P) {
    int h4 = (blockIdx.x * 256 + threadIdx.x) * 4;
    int c = blockIdx.y;
    f32x4 a = *(const f32x4*)(pa + h4);
    f32x4 b = *(const f32x4*)(pb + h4);
    f32x4 h1 = *(const f32x4*)(P + (size_t)c * N_DIM + h4);
    f32x4 h2 = *(const f32x4*)(P + (size_t)c * N_DIM + H_DIM + h4);
    const unsigned short* pb16 = (const unsigned short*)v + (size_t)c * CHUNK * N_DIM + h4;
    const float* pf = (const float*)v + (size_t)c * CHUNK * N_DIM + h4;
    float* po = out + (size_t)c * CHUNK * N_DIM + h4;
#pragma unroll 8
    for (int t = 0; t < CHUNK; t++) {
        f32x4 v1, v2;
        if (BF16IN) {
            uint2 u1 = *(const uint2*)(pb16);
            uint2 u2 = *(const uint2*)(pb16 + H_DIM);
            v1 = (f32x4){blo(u1.x), bhi(u1.x), blo(u1.y), bhi(u1.y)};
            v2 = (f32x4){blo(u2.x), bhi(u2.x), blo(u2.y), bhi(u2.y)};
            pb16 += N_DIM;
        } else {
            v1 = *(const f32x4*)(pf);
            v2 = *(const f32x4*)(pf + H_DIM);
            pf += N_DIM;
        }
        CSTEP(a.x, b.x, h1.x, h2.x, v1.x, v2.x);
        CSTEP(a.y, b.y, h1.y, h2.y, v1.y, v2.y);
        CSTEP(a.z, b.z, h1.z, h2.z, v1.z, v2.z);
        CSTEP(a.w, b.w, h1.w, h2.w, v1.w, v2.w);
        __builtin_nontemporal_store(h1, (f32x4*)(po));
        __builtin_nontemporal_store(h2, (f32x4*)(po + H_DIM));
        po += N_DIM;
    }
}

// ---------------- launcher ----------------
// Fused path ws layout (needs 97 MiB):
//   [0,8Mi)    Bi (interleaved bf16 B)    [8Mi,+24Ki) pa,pb,pg
//   [9Mi,25Mi) xb   [25Mi,89Mi) V (bf16 v)   [89Mi,93Mi) E   [93Mi,97Mi) P
// Fallback = R5 proven layout (89.4 MiB) or fp32-in-out path.

extern "C" void kernel_launch(void* const* d_in, const int* in_sizes, int n_in,
                              void* d_out, int out_size, void* d_ws, size_t ws_size,
                              hipStream_t stream) {
    const float* x     = (const float*)d_in[0];
    const float* lamda = (const float*)d_in[1];
    const float* theta = (const float*)d_in[2];
    const float* B1    = (const float*)d_in[3];
    const float* B2    = (const float*)d_in[4];
    float* out = (float*)d_out;

    char* ws = (char*)d_ws;
    const size_t MiB = 1024 * 1024;
    const size_t need_fused = 97 * MiB;
    const size_t need_bf16  = 25 * MiB + (size_t)T_DIM * N_DIM * 2;  // R5 layout

    if (ws_size >= need_fused) {
        unsigned short* Bi = (unsigned short*)ws;                       // 8 MiB
        float* pa = (float*)(ws + 8 * MiB);
        float* pb = pa + H_DIM;
        float* pg = pb + H_DIM;
        unsigned short* xb = (unsigned short*)(ws + 9 * MiB);           // 16 MiB
        unsigned short* V  = (unsigned short*)(ws + 25 * MiB);          // 64 MiB
        float* E = (float*)(ws + 89 * MiB);                             // 4 MiB
        float* P = (float*)(ws + 93 * MiB);                             // 4 MiB

        hipLaunchKernelGGL(params_kernel, dim3(H_DIM / 256), dim3(256), 0, stream,
                           lamda, theta, pa, pb, pg);
        hipLaunchKernelGGL(cvt_x, dim3((T_DIM * D_DIM / 4) / 256), dim3(256), 0, stream,
                           (const float4*)x, (ushort4*)xb, T_DIM * D_DIM / 4);
        hipLaunchKernelGGL(cvt_B, dim3((2 * H_DIM * D_DIM / 4) / 256), dim3(256), 0, stream,
                           (const float4*)B1, (const float4*)B2, (ushort4*)Bi, 1);
        hipLaunchKernelGGL(gemm_fused256, dim3(T_DIM / 256, N_DIM / 256), dim3(512), 0, stream,
                           xb, Bi, pg, pa, pb, V, E);
        hipLaunchKernelGGL(scanB_wave, dim3(H_DIM / 4), dim3(256), 0, stream, pa, pb, E, P);
        dim3 sgrid(H_DIM / 4 / 256, NCH);
        hipLaunchKernelGGL(scanC_int, sgrid, dim3(256), 0, stream, V, out, pa, pb, P);
        return;
    }

    // ---------- fallback paths (R5, proven) ----------
    unsigned short* xb = (unsigned short*)ws;                              // 16 MiB
    float* E  = (float*)ws;                                                // aliases xb
    float* P  = (float*)(ws + 4 * MiB);                                    // aliases xb
    unsigned short* Bb = (unsigned short*)(ws + 16 * MiB);                 // 8 MiB
    float* pa = (float*)(ws + 24 * MiB);
    float* pb = pa + H_DIM;
    float* pg = pb + H_DIM;
    unsigned short* vb = (unsigned short*)(ws + 25 * MiB);                 // 64 MiB
    const bool use_bf16 = (ws_size >= need_bf16);

    hipLaunchKernelGGL(params_kernel, dim3(H_DIM / 256), dim3(256), 0, stream,
                       lamda, theta, pa, pb, pg);
    hipLaunchKernelGGL(cvt_x, dim3((T_DIM * D_DIM / 4) / 256), dim3(256), 0, stream,
                       (const float4*)x, (ushort4*)xb, T_DIM * D_DIM / 4);
    hipLaunchKernelGGL(cvt_B, dim3((2 * H_DIM * D_DIM / 4) / 256), dim3(256), 0, stream,
                       (const float4*)B1, (const float4*)B2, (ushort4*)Bb, 0);

    dim3 sgrid(H_DIM / 4 / 256, NCH);
    if (use_bf16) {
        gemm_bt<true><<<dim3(T_DIM / 128, N_DIM / 128), dim3(256), 0, stream>>>(xb, Bb, pg, (void*)vb);
        scanA<true><<<sgrid, dim3(256), 0, stream>>>(vb, pa, pb, E);
        hipLaunchKernelGGL(scanB_wave, dim3(H_DIM / 4), dim3(256), 0, stream, pa, pb, E, P);
        scanC<true><<<sgrid, dim3(256), 0, stream>>>(vb, out, pa, pb, P);
    } else {
        gemm_bt<false><<<dim3(T_DIM / 128, N_DIM / 128), dim3(256), 0, stream>>>(xb, Bb, pg, (void*)out);
        scanA<false><<<sgrid, dim3(256), 0, stream>>>(out, pa, pb, E);
        hipLaunchKernelGGL(scanB_wave, dim3(H_DIM / 4), dim3(256), 0, stream, pa, pb, E, P);
        scanC<false><<<sgrid, dim3(256), 0, stream>>>(out, out, pa, pb, P);
    }
}

// Round 3
// 274.588 us; speedup vs baseline: 1.0216x; 1.0216x over previous
//
#include <hip/hip_runtime.h>

#define T_DIM 8192
#define D_DIM 1024
#define H_DIM 2048
#define N_DIM 4096
#define CHUNK 32
#define LOG2_CHUNK 5
#define NCH   (T_DIM / CHUNK)   // 256

typedef __attribute__((ext_vector_type(8))) short bf16x8;
typedef __attribute__((ext_vector_type(4))) float f32x4;

// ---------------- helpers ----------------

__device__ __forceinline__ unsigned short f2bf(float f) {
    unsigned int u = __float_as_uint(f);
    unsigned int r = (u + 0x7fffu + ((u >> 16) & 1u)) >> 16;  // RNE
    return (unsigned short)r;
}

__device__ __forceinline__ float blo(unsigned int u) { return __uint_as_float(u << 16); }
__device__ __forceinline__ float bhi(unsigned int u) { return __uint_as_float(u & 0xffff0000u); }
__device__ __forceinline__ float bf2f(unsigned short u) {
    return __uint_as_float((unsigned int)u << 16);
}

__device__ __forceinline__ void gl_lds16(const unsigned short* g, unsigned short* l) {
    __builtin_amdgcn_global_load_lds(
        (__attribute__((address_space(1))) void*)(g),
        (__attribute__((address_space(3))) void*)(l), 16, 0, 0);
}

// complex rotate-accumulate: (H1+iH2) = (A+iB)(H1+iH2) + (V1+iV2)
#define CSTEP(A, Bq, H1, H2, V1, V2)                  \
    {                                                 \
        float n1 = (A) * (H1) - (Bq) * (H2) + (V1);   \
        float n2 = (A) * (H2) + (Bq) * (H1) + (V2);   \
        (H1) = n1; (H2) = n2;                         \
    }

// ---------------- kernel 1: per-channel params ----------------

__global__ void params_kernel(const float* __restrict__ lamda,
                              const float* __restrict__ theta,
                              float* __restrict__ pa, float* __restrict__ pb,
                              float* __restrict__ pg) {
    int h = blockIdx.x * 256 + threadIdx.x;
    if (h >= H_DIM) return;
    float y = expf(-expf(lamda[h]));
    float z = expf(theta[h]);
    pg[h] = sqrtf(1.0f - y * y);
    pa[h] = y * cosf(z);
    pb[h] = y * sinf(z);
}

// ---------------- kernel 2a: x fp32->bf16 ----------------

__global__ void cvt_x(const float4* __restrict__ s, ushort4* __restrict__ d, int n4) {
    int i = blockIdx.x * 256 + threadIdx.x;
    if (i >= n4) return;
    float4 f = s[i];
    ushort4 o;
    o.x = f2bf(f.x); o.y = f2bf(f.y); o.z = f2bf(f.z); o.w = f2bf(f.w);
    d[i] = o;
}

// ---------------- kernel 2b: B1/B2 fp32->bf16 ----------------
// inter=1: per-channel interleave — dest row = 2*h + comp (so GEMM tile col
//          == V col == 2*ch+comp). inter=0: contiguous [B1; B2] (fallback).

__global__ void cvt_B(const float4* __restrict__ s1, const float4* __restrict__ s2,
                      ushort4* __restrict__ d, int inter) {
    const int n = H_DIM * D_DIM / 4;   // groups per matrix
    int i = blockIdx.x * 256 + threadIdx.x;
    const float4* s; int comp, j;
    if (i < n) { s = s1; comp = 0; j = i; }
    else if (i < 2 * n) { s = s2; comp = 1; j = i - n; }
    else return;
    float4 f = s[j];
    ushort4 o;
    o.x = f2bf(f.x); o.y = f2bf(f.y); o.z = f2bf(f.z); o.w = f2bf(f.w);
    int h = j >> 8;          // 256 float4-groups per 1024-row
    int d4 = j & 255;
    int drow = inter ? (h * 2 + comp)
                     : (comp * H_DIM + h);
    d[(size_t)drow * 256 + d4] = o;
}

// ---------------- kernel 3 (fused path): 256x256 4-phase GEMM + scan epilogue ----
// BM=BN=256, iter = K=128 (2 K-tiles of 64), 8 waves (2M x 4N), 512 thr, 128 KiB LDS.
// LDS map (ushorts): A-even @0, B-even @16384, A-odd @32768, B-odd @49152.
// 4 merged phases/iter (32 MFMA each), 8 barriers/iter (halved vs 8-phase).
// Region liveness (reads): Be:P01 only; Ae:P01+P23; Bo:P45 only; Ao:P45+P67.
// Fills (issue after last-reader phase's end barrier):
//   P01: Ao   [k0+64]   (this iter, read P45)        — 2-phase cover
//   P23: Be'  [k0+128]  (next iter, read P01')       — 3-phase cover  [j<7]
//   P45: Ae'  [k0+128]  (next iter, read P01')       — 2-phase cover  [j<7]
//   P67: Bo'  [k0+192]  (next iter, read P45')       — 2-phase cover  [j<7]
// Waits: VMC4 end of P23 (retires Bo-prev + Ao; j==7: VMC0), VMC4 end of P67
// (retires Ao, Be', Ae'; leaves Bo' 4). Never drains mid-loop.

#define PH_BAR  __builtin_amdgcn_s_barrier()
#define LGKM0   asm volatile("s_waitcnt lgkmcnt(0)" ::: "memory")
#define VMC4    asm volatile("s_waitcnt vmcnt(4)" ::: "memory")
#define VMC0    asm volatile("s_waitcnt vmcnt(0)" ::: "memory")

#define LDA(ABASE, MIB)                                                           \
    { _Pragma("unroll") for (int u = 0; u < 4; ++u)                               \
        { _Pragma("unroll") for (int ks = 0; ks < 2; ++ks)                        \
            af[u][ks] = *(const bf16x8*)&smem[(ABASE) + ks * 8192 + aRd + ((MIB) + u) * 512]; } }

#define LDB(BBASE, NIB)                                                           \
    { _Pragma("unroll") for (int u = 0; u < 2; ++u)                               \
        { _Pragma("unroll") for (int ks = 0; ks < 2; ++ks)                        \
            bfr[(NIB) + u][ks] = *(const bf16x8*)&smem[(BBASE) + ks * 8192 + bRd + ((NIB) + u) * 512]; } }

// merged quadrant-pair: 4mi x 4ni x 2ks = 32 MFMA in one setprio region
#define MFQ2(MIB)                                                                 \
    { __builtin_amdgcn_s_setprio(1);                                              \
      _Pragma("unroll") for (int mi2 = 0; mi2 < 4; ++mi2)                         \
        { _Pragma("unroll") for (int ni2 = 0; ni2 < 4; ++ni2)                     \
            { _Pragma("unroll") for (int ks = 0; ks < 2; ++ks)                    \
                acc[(MIB) + mi2][ni2] = __builtin_amdgcn_mfma_f32_16x16x32_bf16(  \
                    af[mi2][ks], bfr[ni2][ks], acc[(MIB) + mi2][ni2], 0, 0, 0); } } \
      __builtin_amdgcn_s_setprio(0); }

#define STG(SRC, LBASE, HALF, KOFF)                                               \
    { gl_lds16((SRC) + (size_t)(HALF) * 128 * D_DIM + (KOFF),                     \
               &smem[(LBASE) + (HALF) * 4096 + ldsT]);                            \
      gl_lds16((SRC) + (size_t)(HALF) * 128 * D_DIM + (KOFF) + 32,                \
               &smem[(LBASE) + 8192 + (HALF) * 4096 + ldsT]); }

__global__ __launch_bounds__(512, 2) void gemm_fused256(
    const unsigned short* __restrict__ A,    // [8192,1024] bf16
    const unsigned short* __restrict__ Bi,   // interleaved [4096,1024] bf16
    const float* __restrict__ gamma,         // [2048]
    const float* __restrict__ pa, const float* __restrict__ pb,
    unsigned short* __restrict__ V,          // bf16 [8192][4096] (col = 2*ch+comp)
    float* __restrict__ E)                   // [256][4096]
{
    __shared__ unsigned short smem[65536];   // 128 KiB (staging; epilogue aliases as tile)

    const int tid  = threadIdx.x;
    const int lane = tid & 63;
    const int wave = tid >> 6;
    const int quad = lane >> 4;
    const int m16  = lane & 15;
    const int wr   = wave >> 2;   // 0..1 (M)
    const int wc   = wave & 3;    // 0..3 (N)

    // XCD-aware swizzle: XCD k owns a 4-wide bx strip (A slice 2 MiB -> L2-resident).
    const int fid = blockIdx.y * 32 + blockIdx.x;
    const int xcd = fid & 7;
    const int c_  = fid >> 3;            // 0..63
    const int bx  = xcd * 4 + (c_ & 3);  // 0..31
    const int by  = c_ >> 2;             // 0..15

    const int rowA0 = bx * 256;
    const int rowB0 = by * 256;
    const int ch0   = by * 128;

    // staging source mapping (per-thread, linear-lane LDS dest)
    const int r_loc = tid >> 2;                          // 0..127
    const int kg    = ((tid & 3) ^ ((r_loc >> 1) & 3)) * 8;
    const unsigned short* aSrc = A  + (size_t)(rowA0 + r_loc) * D_DIM + kg;
    const unsigned short* bSrc = Bi + (size_t)(rowB0 + r_loc) * D_DIM + kg;
    const int ldsT = tid * 8;

    // fragment read offsets (proven conflict-free pattern)
    const int grp8 = (quad ^ ((m16 >> 1) & 3)) * 8;
    const int aRd  = (wr * 128 + m16) * 32 + grp8;
    const int bRd  = (wc * 64 + m16) * 32 + grp8;

    f32x4 acc[8][4];
#pragma unroll
    for (int i = 0; i < 8; i++)
#pragma unroll
        for (int j = 0; j < 4; j++) acc[i][j] = (f32x4)(0.0f);

    bf16x8 af[4][2], bfr[4][2];

    // prologue: Be, Ae (waited), Bo (left in flight). Ao is filled at P01(0).
    STG(bSrc, 16384, 0, 0);  STG(bSrc, 16384, 1, 0);   // Be  4 loads
    STG(aSrc, 0, 0, 0);      STG(aSrc, 0, 1, 0);       // Ae  4 loads
    STG(bSrc, 49152, 0, 64); STG(bSrc, 49152, 1, 64);  // Bo  4 loads
    VMC4;                    // Be+Ae landed; Bo still in flight
    PH_BAR;

#pragma unroll 1
    for (int j = 0; j < 8; ++j) {
        const int k0 = j * 128;
        // ---- P01 ---- reads Ae(mi0-3)+Be(all); fills Ao[k0+64] (read at P45)
        LDA(0, 0); LDB(16384, 0); LDB(16384, 2);
        STG(aSrc, 32768, 0, k0 + 64); STG(aSrc, 32768, 1, k0 + 64);
        PH_BAR; LGKM0;
        MFQ2(0);
        PH_BAR;
        // ---- P23 ---- reads Ae(mi4-7); fills Be'[k0+128]
        LDA(0, 4);
        if (j < 7) { STG(bSrc, 16384, 0, k0 + 128); STG(bSrc, 16384, 1, k0 + 128); }
        PH_BAR; LGKM0;
        MFQ2(4);
        if (j < 7) { VMC4; } else { VMC0; }   // retire Bo-prev + Ao (P45 needs them)
        PH_BAR;
        // ---- P45 ---- reads Ao(mi0-3)+Bo(all); fills Ae'[k0+128]
        LDA(32768, 0); LDB(49152, 0); LDB(49152, 2);
        if (j < 7) { STG(aSrc, 0, 0, k0 + 128); STG(aSrc, 0, 1, k0 + 128); }
        PH_BAR; LGKM0;
        MFQ2(0);
        PH_BAR;
        // ---- P67 ---- reads Ao(mi4-7); fills Bo'[k0+192]
        LDA(32768, 4);
        if (j < 7) { STG(bSrc, 49152, 0, k0 + 192); STG(bSrc, 49152, 1, k0 + 192); }
        PH_BAR; LGKM0;
        MFQ2(4);
        if (j < 7) { VMC4; }                  // retire Ao+Be'+Ae' (P01' needs Be',Ae')
        PH_BAR;
    }

    __syncthreads();   // full drain; smem reused as 256x256 bf16 output tile

    // ---- acc -> LDS tile (bf16, gamma-scaled), stride 256, quad-XOR col swizzle ----
    // t = wr*128 + mi*16 + quad*4 + r ; col = wc*64 + ni*16 + m16
    // tile col c -> channel ch0 + (c>>1), comp = c&1
#pragma unroll
    for (int ni = 0; ni < 4; ni++) {
        const int col = wc * 64 + ni * 16 + m16;
        const float g = gamma[ch0 + (col >> 1)];
#pragma unroll
        for (int mi = 0; mi < 8; mi++) {
#pragma unroll
            for (int r = 0; r < 4; r++) {
                const int t  = wr * 128 + mi * 16 + quad * 4 + r;
                const int sw = (((t >> 2) & 3) * 48) & 63;
                smem[t * 256 + (col ^ sw)] = f2bf(acc[mi][ni][r] * g);
            }
        }
    }
    __syncthreads();

    // ---- chunk-local scans: 512 threads = 128 channels x 4 chunk-slots, 2 chunks each.
    // Channel chl lives at adjacent tile cols (2chl, 2chl+1) -> one u32 read/step.
    {
        const int chl = tid & 127;
        const int ck4 = tid >> 7;                               // 0..3
        const float wa = pa[ch0 + chl], wb = pb[ch0 + chl];
        const int cbase = chl * 2;
#pragma unroll
        for (int cc = 0; cc < 2; cc++) {
            const int c = ck4 + cc * 4;                         // chunk in block 0..7
            float e1 = 0.f, e2 = 0.f;
#pragma unroll
            for (int jj = 0; jj < CHUNK; jj++) {
                const int t  = c * CHUNK + jj;
                const int sw = (((t >> 2) & 3) * 48) & 63;      // wave-uniform
                unsigned int u = *(const unsigned int*)&smem[t * 256 + (cbase ^ sw)];
                float v1 = blo(u), v2 = bhi(u);
                CSTEP(wa, wb, e1, e2, v1, v2);
            }
            const int cg = bx * 8 + c;
            E[(size_t)cg * N_DIM + ch0 + chl]         = e1;
            E[(size_t)cg * N_DIM + H_DIM + ch0 + chl] = e2;
        }
    }

    // ---- stream tile -> V (bf16, 16B stores). Identity col mapping: V col = by*256 + c.
#pragma unroll
    for (int s = 0; s < 16; s++) {
        const int g     = s * 512 + tid;
        const int row   = g >> 5;
        const int col16 = (g & 31) * 8;
        const int sw    = (((row >> 2) & 3) * 48) & 63;
        uint4 val = *(const uint4*)&smem[row * 256 + (col16 ^ sw)];
        *(uint4*)&V[(size_t)(rowA0 + row) * N_DIM + by * 256 + col16] = val;
    }
}

// ---------------- kernel 3 (fallback): R5 gemm ----------------

template <bool BF16OUT>
__global__ __launch_bounds__(256) void gemm_bt(
    const unsigned short* __restrict__ A, const unsigned short* __restrict__ B,
    const float* __restrict__ gamma, void* __restrict__ Cv)
{
    __shared__ unsigned short sA[128 * 32];
    __shared__ unsigned short sB[128 * 32];

    const int tid  = threadIdx.x;
    const int lane = tid & 63;
    const int wave = tid >> 6;
    const int quad = lane >> 4;
    const int m16  = lane & 15;
    const int wm = (wave >> 1) << 6;
    const int wn = (wave & 1) << 6;
    const int rowA0 = blockIdx.x * 128;
    const int rowB0 = blockIdx.y * 128;
    const int e0 = tid * 8;
    const int r0 = e0 >> 5;
    const int gs = (e0 >> 3) & 3;
    const int k0 = (gs ^ ((r0 >> 1) & 3)) * 8;
    const int r1 = r0 + 64;
    const unsigned short* a0 = A + (size_t)(rowA0 + r0) * D_DIM + k0;
    const unsigned short* a1 = A + (size_t)(rowA0 + r1) * D_DIM + k0;
    const unsigned short* b0 = B + (size_t)(rowB0 + r0) * D_DIM + k0;
    const unsigned short* b1 = B + (size_t)(rowB0 + r1) * D_DIM + k0;
    unsigned short* la0 = &sA[e0];
    unsigned short* la1 = &sA[e0 + 2048];
    unsigned short* lb0 = &sB[e0];
    unsigned short* lb1 = &sB[e0 + 2048];
    const int grp8 = (quad ^ ((m16 >> 1) & 3)) * 8;

    f32x4 acc[4][4];
#pragma unroll
    for (int i = 0; i < 4; i++)
#pragma unroll
        for (int j = 0; j < 4; j++) acc[i][j] = (f32x4)(0.0f);

    for (int kt = 0; kt < D_DIM; kt += 32) {
        __syncthreads();
        gl_lds16(a0 + kt, la0);
        gl_lds16(a1 + kt, la1);
        gl_lds16(b0 + kt, lb0);
        gl_lds16(b1 + kt, lb1);
        __syncthreads();
        bf16x8 af2[4], bfr2[4];
#pragma unroll
        for (int i = 0; i < 4; i++)
            af2[i] = *(const bf16x8*)&sA[(wm + i * 16 + m16) * 32 + grp8];
#pragma unroll
        for (int i = 0; i < 4; i++)
            bfr2[i] = *(const bf16x8*)&sB[(wn + i * 16 + m16) * 32 + grp8];
#pragma unroll
        for (int mi = 0; mi < 4; mi++)
#pragma unroll
            for (int ni = 0; ni < 4; ni++)
                acc[mi][ni] = __builtin_amdgcn_mfma_f32_16x16x32_bf16(
                    af2[mi], bfr2[ni], acc[mi][ni], 0, 0, 0);
    }

    float* Cf = (float*)Cv;
    unsigned short* Cb = (unsigned short*)Cv;
#pragma unroll
    for (int ni = 0; ni < 4; ni++) {
        const int col = rowB0 + wn + ni * 16 + m16;
        const float g = gamma[col & (H_DIM - 1)];
#pragma unroll
        for (int mi = 0; mi < 4; mi++) {
            const int row0 = rowA0 + wm + mi * 16 + quad * 4;
#pragma unroll
            for (int r = 0; r < 4; r++) {
                float val = acc[mi][ni][r] * g;
                if (BF16OUT) Cb[(size_t)(row0 + r) * N_DIM + col] = f2bf(val);
                else         Cf[(size_t)(row0 + r) * N_DIM + col] = val;
            }
        }
    }
}

// ---------------- kernel 4a (fallback): chunk-local end states ----------------

template <bool BF16IN>
__global__ void scanA(const void* __restrict__ v,
                      const float* __restrict__ pa, const float* __restrict__ pb,
                      float* __restrict__ E) {
    int h4 = (blockIdx.x * 256 + threadIdx.x) * 4;
    int c = blockIdx.y;
    float4 a = *(const float4*)(pa + h4);
    float4 b = *(const float4*)(pb + h4);
    float4 h1 = make_float4(0.f, 0.f, 0.f, 0.f);
    float4 h2 = make_float4(0.f, 0.f, 0.f, 0.f);
    const unsigned short* pb16 = (const unsigned short*)v + (size_t)c * CHUNK * N_DIM + h4;
    const float* pf = (const float*)v + (size_t)c * CHUNK * N_DIM + h4;
#pragma unroll 8
    for (int t = 0; t < CHUNK; t++) {
        float4 v1, v2;
        if (BF16IN) {
            uint2 u1 = *(const uint2*)(pb16);
            uint2 u2 = *(const uint2*)(pb16 + H_DIM);
            v1 = make_float4(blo(u1.x), bhi(u1.x), blo(u1.y), bhi(u1.y));
            v2 = make_float4(blo(u2.x), bhi(u2.x), blo(u2.y), bhi(u2.y));
            pb16 += N_DIM;
        } else {
            v1 = *(const float4*)(pf);
            v2 = *(const float4*)(pf + H_DIM);
            pf += N_DIM;
        }
        CSTEP(a.x, b.x, h1.x, h2.x, v1.x, v2.x);
        CSTEP(a.y, b.y, h1.y, h2.y, v1.y, v2.y);
        CSTEP(a.z, b.z, h1.z, h2.z, v1.z, v2.z);
        CSTEP(a.w, b.w, h1.w, h2.w, v1.w, v2.w);
    }
    *(float4*)(E + (size_t)c * N_DIM + h4)         = h1;
    *(float4*)(E + (size_t)c * N_DIM + H_DIM + h4) = h2;
}

// ---------------- kernel 4b: wave-parallel carry scan (one wave per channel) ----------------

__global__ __launch_bounds__(256) void scanB_wave(
    const float* __restrict__ pa, const float* __restrict__ pb,
    const float* __restrict__ E, float* __restrict__ P) {
    const int lane = threadIdx.x & 63;
    const int ch   = blockIdx.x * 4 + (threadIdx.x >> 6);
    const float ca = pa[ch], cb = pb[ch];
    float Wr = ca, Wi = cb;
#pragma unroll
    for (int j = 0; j < LOG2_CHUNK; j++) {
        float nr = Wr * Wr - Wi * Wi, ni = 2.f * Wr * Wi;
        Wr = nr; Wi = ni;
    }
    float Sr[4], Si[4];
    float sr = 0.f, si = 0.f;
#pragma unroll
    for (int k = 0; k < 4; k++) {
        int cc = 4 * lane + k;
        float e1 = E[(size_t)cc * N_DIM + ch];
        float e2 = E[(size_t)cc * N_DIM + H_DIM + ch];
        float nr = Wr * sr - Wi * si + e1;
        float ni = Wr * si + Wi * sr + e2;
        sr = nr; si = ni;
        Sr[k] = sr; Si[k] = si;
    }
    float vr = sr, vi = si;
    float W4r = Wr * Wr - Wi * Wi, W4i = 2.f * Wr * Wi;
    { float nr = W4r * W4r - W4i * W4i, ni = 2.f * W4r * W4i;
      W4r = nr; W4i = ni; }
    float stepR = W4r, stepI = W4i;
#pragma unroll
    for (int d = 1; d < 64; d <<= 1) {
        float tr = __shfl_up(vr, d, 64);
        float ti = __shfl_up(vi, d, 64);
        float nr = stepR * tr - stepI * ti + vr;
        float ni = stepR * ti + stepI * tr + vi;
        if (lane >= d) { vr = nr; vi = ni; }
        float r2 = stepR * stepR - stepI * stepI;
        float i2 = 2.f * stepR * stepI;
        stepR = r2; stepI = i2;
    }
    float txr = __shfl_up(vr, 1, 64);
    float txi = __shfl_up(vi, 1, 64);
    if (lane == 0) { txr = 0.f; txi = 0.f; }
    P[(size_t)(4 * lane) * N_DIM + ch]         = txr;
    P[(size_t)(4 * lane) * N_DIM + H_DIM + ch] = txi;
    float qr = txr, qi = txi;
#pragma unroll
    for (int k = 1; k < 4; k++) {
        float nr = Wr * qr - Wi * qi;
        float ni = Wr * qi + Wi * qr;
        qr = nr; qi = ni;
        P[(size_t)(4 * lane + k) * N_DIM + ch]         = qr + Sr[k - 1];
        P[(size_t)(4 * lane + k) * N_DIM + H_DIM + ch] = qi + Si[k - 1];
    }
}

// ---------------- kernel 4c (fused path): final scan, interleaved V, uint4 loads ----

__global__ void scanC_int(const unsigned short* __restrict__ v, float* __restrict__ out,
                          const float* __restrict__ pa, const float* __restrict__ pb,
                          const float* __restrict__ P) {
    int ch4 = (blockIdx.x * 256 + threadIdx.x) * 4;
    int c = blockIdx.y;
    f32x4 a = *(const f32x4*)(pa + ch4);
    f32x4 b = *(const f32x4*)(pb + ch4);
    f32x4 h1 = *(const f32x4*)(P + (size_t)c * N_DIM + ch4);
    f32x4 h2 = *(const f32x4*)(P + (size_t)c * N_DIM + H_DIM + ch4);
    const unsigned short* pv = v + (size_t)c * CHUNK * N_DIM + (size_t)ch4 * 2;
    float* po = out + (size_t)c * CHUNK * N_DIM + ch4;
#pragma unroll 8
    for (int t = 0; t < CHUNK; t++) {
        uint4 u = *(const uint4*)pv;
        f32x4 v1 = {blo(u.x), blo(u.y), blo(u.z), blo(u.w)};
        f32x4 v2 = {bhi(u.x), bhi(u.y), bhi(u.z), bhi(u.w)};
        CSTEP(a.x, b.x, h1.x, h2.x, v1.x, v2.x);
        CSTEP(a.y, b.y, h1.y, h2.y, v1.y, v2.y);
        CSTEP(a.z, b.z, h1.z, h2.z, v1.z, v2.z);
        CSTEP(a.w, b.w, h1.w, h2.w, v1.w, v2.w);
        __builtin_nontemporal_store(h1, (f32x4*)(po));
        __builtin_nontemporal_store(h2, (f32x4*)(po + H_DIM));
        pv += N_DIM; po += N_DIM;
    }
}

// ---------------- kernel 4c (fallback): final scan, separate-comp layout ----------------

template <bool BF16IN>
__global__ void scanC(const void* __restrict__ v, float* __restrict__ out,
                      const float* __restrict__ pa, const float* __restrict__ pb,
                      const float* __restrict__ P) {
    int h4 = (blockIdx.x * 256 + threadIdx.x) * 4;
    int c = blockIdx.y;
    f32x4 a = *(const f32x4*)(pa + h4);
    f32x4 b = *(const f32x4*)(pb + h4);
    f32x4 h1 = *(const f32x4*)(P + (size_t)c * N_DIM + h4);
    f32x4 h2 = *(const f32x4*)(P + (size_t)c * N_DIM + H_DIM + h4);
    const unsigned short* pb16 = (const unsigned short*)v + (size_t)c * CHUNK * N_DIM + h4;
    const float* pf = (const float*)v + (size_t)c * CHUNK * N_DIM + h4;
    float* po = out + (size_t)c * CHUNK * N_DIM + h4;
#pragma unroll 8
    for (int t = 0; t < CHUNK; t++) {
        f32x4 v1, v2;
        if (BF16IN) {
            uint2 u1 = *(const uint2*)(pb16);
            uint2 u2 = *(const uint2*)(pb16 + H_DIM);
            v1 = (f32x4){blo(u1.x), bhi(u1.x), blo(u1.y), bhi(u1.y)};
            v2 = (f32x4){blo(u2.x), bhi(u2.x), blo(u2.y), bhi(u2.y)};
            pb16 += N_DIM;
        } else {
            v1 = *(const f32x4*)(pf);
            v2 = *(const f32x4*)(pf + H_DIM);
            pf += N_DIM;
        }
        CSTEP(a.x, b.x, h1.x, h2.x, v1.x, v2.x);
        CSTEP(a.y, b.y, h1.y, h2.y, v1.y, v2.y);
        CSTEP(a.z, b.z, h1.z, h2.z, v1.z, v2.z);
        CSTEP(a.w, b.w, h1.w, h2.w, v1.w, v2.w);
        __builtin_nontemporal_store(h1, (f32x4*)(po));
        __builtin_nontemporal_store(h2, (f32x4*)(po + H_DIM));
        po += N_DIM;
    }
}

// ---------------- launcher ----------------
// Fused path ws layout (needs 97 MiB):
//   [0,8Mi)    Bi (interleaved bf16 B)    [8Mi,+24Ki) pa,pb,pg
//   [9Mi,25Mi) xb   [25Mi,89Mi) V (bf16 v)   [89Mi,93Mi) E   [93Mi,97Mi) P
// Fallback = R5 proven layout (89.4 MiB) or fp32-in-out path.

extern "C" void kernel_launch(void* const* d_in, const int* in_sizes, int n_in,
                              void* d_out, int out_size, void* d_ws, size_t ws_size,
                              hipStream_t stream) {
    const float* x     = (const float*)d_in[0];
    const float* lamda = (const float*)d_in[1];
    const float* theta = (const float*)d_in[2];
    const float* B1    = (const float*)d_in[3];
    const float* B2    = (const float*)d_in[4];
    float* out = (float*)d_out;

    char* ws = (char*)d_ws;
    const size_t MiB = 1024 * 1024;
    const size_t need_fused = 97 * MiB;
    const size_t need_bf16  = 25 * MiB + (size_t)T_DIM * N_DIM * 2;  // R5 layout

    if (ws_size >= need_fused) {
        unsigned short* Bi = (unsigned short*)ws;                       // 8 MiB
        float* pa = (float*)(ws + 8 * MiB);
        float* pb = pa + H_DIM;
        float* pg = pb + H_DIM;
        unsigned short* xb = (unsigned short*)(ws + 9 * MiB);           // 16 MiB
        unsigned short* V  = (unsigned short*)(ws + 25 * MiB);          // 64 MiB
        float* E = (float*)(ws + 89 * MiB);                             // 4 MiB
        float* P = (float*)(ws + 93 * MiB);                             // 4 MiB

        hipLaunchKernelGGL(params_kernel, dim3(H_DIM / 256), dim3(256), 0, stream,
                           lamda, theta, pa, pb, pg);
        hipLaunchKernelGGL(cvt_x, dim3((T_DIM * D_DIM / 4) / 256), dim3(256), 0, stream,
                           (const float4*)x, (ushort4*)xb, T_DIM * D_DIM / 4);
        hipLaunchKernelGGL(cvt_B, dim3((2 * H_DIM * D_DIM / 4) / 256), dim3(256), 0, stream,
                           (const float4*)B1, (const float4*)B2, (ushort4*)Bi, 1);
        hipLaunchKernelGGL(gemm_fused256, dim3(T_DIM / 256, N_DIM / 256), dim3(512), 0, stream,
                           xb, Bi, pg, pa, pb, V, E);
        hipLaunchKernelGGL(scanB_wave, dim3(H_DIM / 4), dim3(256), 0, stream, pa, pb, E, P);
        dim3 sgrid(H_DIM / 4 / 256, NCH);
        hipLaunchKernelGGL(scanC_int, sgrid, dim3(256), 0, stream, V, out, pa, pb, P);
        return;
    }

    // ---------- fallback paths (R5, proven) ----------
    unsigned short* xb = (unsigned short*)ws;                              // 16 MiB
    float* E  = (float*)ws;                                                // aliases xb
    float* P  = (float*)(ws + 4 * MiB);                                    // aliases xb
    unsigned short* Bb = (unsigned short*)(ws + 16 * MiB);                 // 8 MiB
    float* pa = (float*)(ws + 24 * MiB);
    float* pb = pa + H_DIM;
    float* pg = pb + H_DIM;
    unsigned short* vb = (unsigned short*)(ws + 25 * MiB);                 // 64 MiB
    const bool use_bf16 = (ws_size >= need_bf16);

    hipLaunchKernelGGL(params_kernel, dim3(H_DIM / 256), dim3(256), 0, stream,
                       lamda, theta, pa, pb, pg);
    hipLaunchKernelGGL(cvt_x, dim3((T_DIM * D_DIM / 4) / 256), dim3(256), 0, stream,
                       (const float4*)x, (ushort4*)xb, T_DIM * D_DIM / 4);
    hipLaunchKernelGGL(cvt_B, dim3((2 * H_DIM * D_DIM / 4) / 256), dim3(256), 0, stream,
                       (const float4*)B1, (const float4*)B2, (ushort4*)Bb, 0);

    dim3 sgrid(H_DIM / 4 / 256, NCH);
    if (use_bf16) {
        gemm_bt<true><<<dim3(T_DIM / 128, N_DIM / 128), dim3(256), 0, stream>>>(xb, Bb, pg, (void*)vb);
        scanA<true><<<sgrid, dim3(256), 0, stream>>>(vb, pa, pb, E);
        hipLaunchKernelGGL(scanB_wave, dim3(H_DIM / 4), dim3(256), 0, stream, pa, pb, E, P);
        scanC<true><<<sgrid, dim3(256), 0, stream>>>(vb, out, pa, pb, P);
    } else {
        gemm_bt<false><<<dim3(T_DIM / 128, N_DIM / 128), dim3(256), 0, stream>>>(xb, Bb, pg, (void*)out);
        scanA<false><<<sgrid, dim3(256), 0, stream>>>(out, pa, pb, E);
        hipLaunchKernelGGL(scanB_wave, dim3(H_DIM / 4), dim3(256), 0, stream, pa, pb, E, P);
        scanC<false><<<sgrid, dim3(256), 0, stream>>>(out, out, pa, pb, P);
    }
}